// Round 2
// baseline (206.365 us; speedup 1.0000x reference)
//
#include <hip/hip_runtime.h>
#include <hip/hip_bf16.h>

#define N_PTS   1024
#define IMG_H   128
#define IMG_W   128
#define NPIX    (IMG_H * IMG_W)
#define NEAR    0.01f
#define NSIGMA2 9.0f
#define COV_BLUR 0.3f
#define NCHUNK  8
#define CHUNK_SZ (N_PTS / NCHUNK)   // 128
#define PT_STRIDE 12                // floats per point record (3 x float4)

// ---------------------------------------------------------------------------
// Kernel A: per-point projection + conic.  Writes AoS record of 12 floats:
//   [tz, u, v, ca | cb, cc, a, r | g, b, 0, 0]
// ---------------------------------------------------------------------------
__global__ __launch_bounds__(256) void k_preprocess(
    const float* __restrict__ coords,
    const float* __restrict__ covs,
    const float* __restrict__ colors,
    const float* __restrict__ alphas,
    const float* __restrict__ Wm,
    const float* __restrict__ Km,
    float* __restrict__ unsorted)
{
    int i = blockIdx.x * blockDim.x + threadIdx.x;
    if (i >= N_PTS) return;

    // W is 4x4 row-major; R = W[:3,:3], t = W[:3,3]
    float R[3][3], tvec[3];
    #pragma unroll
    for (int r = 0; r < 3; r++) {
        #pragma unroll
        for (int c = 0; c < 3; c++) R[r][c] = Wm[r * 4 + c];
        tvec[r] = Wm[r * 4 + 3];
    }
    float fx = Km[0], fy = Km[4], cx = Km[2], cy = Km[5];

    float c0 = coords[i * 3 + 0];
    float c1 = coords[i * 3 + 1];
    float c2 = coords[i * 3 + 2];

    float tx = R[0][0] * c0 + R[0][1] * c1 + R[0][2] * c2 + tvec[0];
    float ty = R[1][0] * c0 + R[1][1] * c1 + R[1][2] * c2 + tvec[1];
    float tz = R[2][0] * c0 + R[2][1] * c1 + R[2][2] * c2 + tvec[2];

    float invz = 1.0f / fmaxf(tz, NEAR);
    float u = fx * tx * invz + cx;
    float v = fy * ty * invz + cy;

    float J00 = fx * invz;
    float J02 = -fx * tx * invz * invz;
    float J11 = fy * invz;
    float J12 = -fy * ty * invz * invz;

    // covariance 3x3
    float S[3][3];
    #pragma unroll
    for (int r = 0; r < 3; r++)
        #pragma unroll
        for (int c = 0; c < 3; c++) S[r][c] = covs[i * 9 + r * 3 + c];

    // sig_cam = R * S * R^T
    float M[3][3];
    #pragma unroll
    for (int r = 0; r < 3; r++)
        #pragma unroll
        for (int c = 0; c < 3; c++)
            M[r][c] = R[r][0] * S[0][c] + R[r][1] * S[1][c] + R[r][2] * S[2][c];
    float Sc[3][3];
    #pragma unroll
    for (int r = 0; r < 3; r++)
        #pragma unroll
        for (int c = 0; c < 3; c++)
            Sc[r][c] = M[r][0] * R[c][0] + M[r][1] * R[c][1] + M[r][2] * R[c][2];

    // sig2d = J * Sc * J^T + COV_BLUR*I   (J is 2x3 with zeros at J01, J10)
    float js0_0 = J00 * Sc[0][0] + J02 * Sc[2][0];
    float js0_1 = J00 * Sc[0][1] + J02 * Sc[2][1];
    float js0_2 = J00 * Sc[0][2] + J02 * Sc[2][2];
    float js1_1 = J11 * Sc[1][1] + J12 * Sc[2][1];
    float js1_2 = J11 * Sc[1][2] + J12 * Sc[2][2];

    float s00 = J00 * js0_0 + J02 * js0_2 + COV_BLUR;
    float s01 = J11 * js0_1 + J12 * js0_2;
    float s11 = J11 * js1_1 + J12 * js1_2 + COV_BLUR;

    float det = s00 * s11 - s01 * s01;
    float invdet = 1.0f / det;
    float ca = s11 * invdet;
    float cc = s00 * invdet;
    float cb = -s01 * invdet;

    float a = fminf(fmaxf(alphas[i], 0.0f), 1.0f);
    if (!(tz > NEAR)) a = 0.0f;   // fold 'valid' mask into alpha

    float* o = unsorted + i * PT_STRIDE;
    o[0] = tz;  o[1] = u;   o[2] = v;  o[3] = ca;
    o[4] = cb;  o[5] = cc;  o[6] = a;  o[7] = colors[i * 3 + 0];
    o[8] = colors[i * 3 + 1];          o[9] = colors[i * 3 + 2];
    o[10] = 0.0f; o[11] = 0.0f;
}

// ---------------------------------------------------------------------------
// Kernel B: stable depth sort via O(N^2) rank counting + scatter.
// Tie-break by original index == stable sort (matches jnp.argsort).
// ---------------------------------------------------------------------------
__global__ __launch_bounds__(64) void k_sort(
    const float* __restrict__ unsorted, float* __restrict__ sorted)
{
    int i = blockIdx.x * blockDim.x + threadIdx.x;  // 0..1023
    float my = unsorted[i * PT_STRIDE];
    int rank = 0;
    for (int j = 0; j < N_PTS; j++) {
        float tj = unsorted[j * PT_STRIDE];
        rank += (tj < my) || (tj == my && j < i);
    }
    const float4* src = (const float4*)(unsorted + i * PT_STRIDE);
    float4* dst = (float4*)(sorted + rank * PT_STRIDE);
    dst[0] = src[0]; dst[1] = src[1]; dst[2] = src[2];
}

// ---------------------------------------------------------------------------
// Kernel C1: per-(pixel, chunk) front-to-back compositing of 128 gaussians.
// Partial state (Cr, Cg, Cb, T) per pixel per chunk; combined later in order.
// Grid: (NPIX/256, NCHUNK) x 256 -> 512 blocks -> 2 blocks/CU, 8 waves/CU.
// ---------------------------------------------------------------------------
__global__ __launch_bounds__(256) void k_composite(
    const float* __restrict__ sorted, float* __restrict__ partials)
{
    int chunk = blockIdx.y;
    int pix = blockIdx.x * 256 + threadIdx.x;

    __shared__ float4 sg[CHUNK_SZ * 3];
    const float4* src = (const float4*)sorted + chunk * CHUNK_SZ * 3;
    for (int idx = threadIdx.x; idx < CHUNK_SZ * 3; idx += 256)
        sg[idx] = src[idx];
    __syncthreads();

    float px = (float)(pix & (IMG_W - 1)) + 0.5f;
    float py = (float)(pix >> 7) + 0.5f;

    float T = 1.0f, cr = 0.0f, cg = 0.0f, cb_acc = 0.0f;
    #pragma unroll 4
    for (int k = 0; k < CHUNK_SZ; k++) {
        float4 A = sg[k * 3 + 0];   // tz, u, v, ca
        float4 B = sg[k * 3 + 1];   // cb, cc, a, r
        float4 C = sg[k * 3 + 2];   // g, b, -, -
        float dx = px - A.y;
        float dy = py - A.z;
        float q  = A.w * dx * dx + B.y * dy * dy + 2.0f * B.x * dx * dy;
        float gs = __expf(-0.5f * q);
        float apx = (q <= NSIGMA2) ? fminf(B.z * gs, 0.999f) : 0.0f;
        float w = T * apx;
        cr     = fmaf(w, B.w, cr);
        cg     = fmaf(w, C.x, cg);
        cb_acc = fmaf(w, C.y, cb_acc);
        T = T * (1.0f - apx);
    }
    ((float4*)partials)[chunk * NPIX + pix] = make_float4(cr, cg, cb_acc, T);
}

// ---------------------------------------------------------------------------
// Kernel C2: fold the NCHUNK partials per pixel in depth order, emit fp32 CHW.
// ---------------------------------------------------------------------------
__global__ __launch_bounds__(256) void k_combine(
    const float* __restrict__ partials, float* __restrict__ out)
{
    int pix = blockIdx.x * 256 + threadIdx.x;
    float T = 1.0f, cr = 0.0f, cg = 0.0f, cb = 0.0f;
    #pragma unroll
    for (int c = 0; c < NCHUNK; c++) {
        float4 p = ((const float4*)partials)[c * NPIX + pix];
        cr = fmaf(T, p.x, cr);
        cg = fmaf(T, p.y, cg);
        cb = fmaf(T, p.z, cb);
        T *= p.w;
    }
    out[0 * NPIX + pix] = cr;
    out[1 * NPIX + pix] = cg;
    out[2 * NPIX + pix] = cb;
}

extern "C" void kernel_launch(void* const* d_in, const int* in_sizes, int n_in,
                              void* d_out, int out_size, void* d_ws, size_t ws_size,
                              hipStream_t stream)
{
    const float* coords = (const float*)d_in[0];
    const float* covs   = (const float*)d_in[1];
    const float* colors = (const float*)d_in[2];
    const float* alphas = (const float*)d_in[3];
    const float* Wm     = (const float*)d_in[4];
    const float* Km     = (const float*)d_in[5];

    float* ws = (float*)d_ws;
    float* unsorted = ws;                             // 1024*12 floats = 48 KB
    float* sorted   = ws + N_PTS * PT_STRIDE;         // 48 KB
    float* partials = ws + 2 * N_PTS * PT_STRIDE;     // 8*16384*4 floats = 2 MB

    k_preprocess<<<dim3((N_PTS + 255) / 256), dim3(256), 0, stream>>>(
        coords, covs, colors, alphas, Wm, Km, unsorted);
    k_sort<<<dim3(N_PTS / 64), dim3(64), 0, stream>>>(unsorted, sorted);
    k_composite<<<dim3(NPIX / 256, NCHUNK), dim3(256), 0, stream>>>(sorted, partials);
    k_combine<<<dim3(NPIX / 256), dim3(256), 0, stream>>>(partials, (float*)d_out);
}

// Round 3
// 114.007 us; speedup vs baseline: 1.8101x; 1.8101x over previous
//
#include <hip/hip_runtime.h>
#include <hip/hip_bf16.h>

#define N_PTS   1024
#define IMG_H   128
#define IMG_W   128
#define NPIX    (IMG_H * IMG_W)
#define NEAR    0.01f
#define NSIGMA2 9.0f
#define COV_BLUR 0.3f
#define NCHUNK  8
#define CHUNK_SZ (N_PTS / NCHUNK)   // 128
#define PT_STRIDE 12                // floats per point record (3 x float4)

// ---------------------------------------------------------------------------
// Kernel A: per-point projection + conic.  Writes AoS record of 12 floats:
//   [tz, u, v, ca | cb, cc, a, r | g, b, 0, 0]
// plus a dense depth array (4 KB) for the sort kernel.
// ---------------------------------------------------------------------------
__global__ __launch_bounds__(256) void k_preprocess(
    const float* __restrict__ coords,
    const float* __restrict__ covs,
    const float* __restrict__ colors,
    const float* __restrict__ alphas,
    const float* __restrict__ Wm,
    const float* __restrict__ Km,
    float* __restrict__ unsorted,
    float* __restrict__ depths)
{
    int i = blockIdx.x * blockDim.x + threadIdx.x;
    if (i >= N_PTS) return;

    float R[3][3], tvec[3];
    #pragma unroll
    for (int r = 0; r < 3; r++) {
        #pragma unroll
        for (int c = 0; c < 3; c++) R[r][c] = Wm[r * 4 + c];
        tvec[r] = Wm[r * 4 + 3];
    }
    float fx = Km[0], fy = Km[4], cx = Km[2], cy = Km[5];

    float c0 = coords[i * 3 + 0];
    float c1 = coords[i * 3 + 1];
    float c2 = coords[i * 3 + 2];

    float tx = R[0][0] * c0 + R[0][1] * c1 + R[0][2] * c2 + tvec[0];
    float ty = R[1][0] * c0 + R[1][1] * c1 + R[1][2] * c2 + tvec[1];
    float tz = R[2][0] * c0 + R[2][1] * c1 + R[2][2] * c2 + tvec[2];

    float invz = 1.0f / fmaxf(tz, NEAR);
    float u = fx * tx * invz + cx;
    float v = fy * ty * invz + cy;

    float J00 = fx * invz;
    float J02 = -fx * tx * invz * invz;
    float J11 = fy * invz;
    float J12 = -fy * ty * invz * invz;

    float S[3][3];
    #pragma unroll
    for (int r = 0; r < 3; r++)
        #pragma unroll
        for (int c = 0; c < 3; c++) S[r][c] = covs[i * 9 + r * 3 + c];

    float M[3][3];
    #pragma unroll
    for (int r = 0; r < 3; r++)
        #pragma unroll
        for (int c = 0; c < 3; c++)
            M[r][c] = R[r][0] * S[0][c] + R[r][1] * S[1][c] + R[r][2] * S[2][c];
    float Sc[3][3];
    #pragma unroll
    for (int r = 0; r < 3; r++)
        #pragma unroll
        for (int c = 0; c < 3; c++)
            Sc[r][c] = M[r][0] * R[c][0] + M[r][1] * R[c][1] + M[r][2] * R[c][2];

    float js0_0 = J00 * Sc[0][0] + J02 * Sc[2][0];
    float js0_1 = J00 * Sc[0][1] + J02 * Sc[2][1];
    float js0_2 = J00 * Sc[0][2] + J02 * Sc[2][2];
    float js1_1 = J11 * Sc[1][1] + J12 * Sc[2][1];
    float js1_2 = J11 * Sc[1][2] + J12 * Sc[2][2];

    float s00 = J00 * js0_0 + J02 * js0_2 + COV_BLUR;
    float s01 = J11 * js0_1 + J12 * js0_2;
    float s11 = J11 * js1_1 + J12 * js1_2 + COV_BLUR;

    float det = s00 * s11 - s01 * s01;
    float invdet = 1.0f / det;
    float ca = s11 * invdet;
    float cc = s00 * invdet;
    float cb = -s01 * invdet;

    float a = fminf(fmaxf(alphas[i], 0.0f), 1.0f);
    if (!(tz > NEAR)) a = 0.0f;   // fold 'valid' mask into alpha

    float* o = unsorted + i * PT_STRIDE;
    o[0] = tz;  o[1] = u;   o[2] = v;  o[3] = ca;
    o[4] = cb;  o[5] = cc;  o[6] = a;  o[7] = colors[i * 3 + 0];
    o[8] = colors[i * 3 + 1];          o[9] = colors[i * 3 + 2];
    o[10] = 0.0f; o[11] = 0.0f;
    depths[i] = tz;
}

// ---------------------------------------------------------------------------
// Kernel B: stable depth sort via O(N^2) rank counting + scatter.
// Depths staged in LDS (4 KB) -> broadcast ds_read per iteration instead of
// a 300-cycle L2-latency-bound global load chain (round-2 bottleneck).
// Tie-break by original index == stable sort (matches jnp.argsort).
// ---------------------------------------------------------------------------
__global__ __launch_bounds__(64) void k_sort(
    const float* __restrict__ unsorted,
    const float* __restrict__ depths,
    float* __restrict__ sorted)
{
    __shared__ float sdep[N_PTS];
    for (int idx = threadIdx.x; idx < N_PTS; idx += 64)
        sdep[idx] = depths[idx];
    __syncthreads();

    int i = blockIdx.x * 64 + threadIdx.x;  // 0..1023
    float my = sdep[i];
    int rank = 0;
    #pragma unroll 16
    for (int j = 0; j < N_PTS; j++) {
        float tj = sdep[j];
        rank += (tj < my) || (tj == my && j < i);
    }
    const float4* src = (const float4*)(unsorted + i * PT_STRIDE);
    float4* dst = (float4*)(sorted + rank * PT_STRIDE);
    dst[0] = src[0]; dst[1] = src[1]; dst[2] = src[2];
}

// ---------------------------------------------------------------------------
// Kernel C1: per-(pixel, chunk) front-to-back compositing of 128 gaussians.
// Gaussian record address is wave-uniform (loop counter only) -> backend
// emits scalar s_load; no LDS, no barriers.
// Grid: (NPIX/256, NCHUNK) x 256 -> 512 blocks -> 2 blocks/CU, 8 waves/CU.
// ---------------------------------------------------------------------------
__global__ __launch_bounds__(256) void k_composite(
    const float* __restrict__ sorted, float* __restrict__ partials)
{
    int chunk = blockIdx.y;
    int pix = blockIdx.x * 256 + threadIdx.x;

    const float4* g = (const float4*)sorted + chunk * CHUNK_SZ * 3;

    float px = (float)(pix & (IMG_W - 1)) + 0.5f;
    float py = (float)(pix >> 7) + 0.5f;

    float T = 1.0f, cr = 0.0f, cg = 0.0f, cb_acc = 0.0f;
    #pragma unroll 8
    for (int k = 0; k < CHUNK_SZ; k++) {
        float4 A = g[k * 3 + 0];   // tz, u, v, ca
        float4 B = g[k * 3 + 1];   // cb, cc, a, r
        float4 C = g[k * 3 + 2];   // g, b, -, -
        float dx = px - A.y;
        float dy = py - A.z;
        float q  = A.w * dx * dx + B.y * dy * dy + 2.0f * B.x * dx * dy;
        float gs = __expf(-0.5f * q);
        float apx = (q <= NSIGMA2) ? fminf(B.z * gs, 0.999f) : 0.0f;
        float w = T * apx;
        cr     = fmaf(w, B.w, cr);
        cg     = fmaf(w, C.x, cg);
        cb_acc = fmaf(w, C.y, cb_acc);
        T = T * (1.0f - apx);
    }
    ((float4*)partials)[chunk * NPIX + pix] = make_float4(cr, cg, cb_acc, T);
}

// ---------------------------------------------------------------------------
// Kernel C2: fold the NCHUNK partials per pixel in depth order, emit fp32 CHW.
// ---------------------------------------------------------------------------
__global__ __launch_bounds__(256) void k_combine(
    const float* __restrict__ partials, float* __restrict__ out)
{
    int pix = blockIdx.x * 256 + threadIdx.x;
    float T = 1.0f, cr = 0.0f, cg = 0.0f, cb = 0.0f;
    #pragma unroll
    for (int c = 0; c < NCHUNK; c++) {
        float4 p = ((const float4*)partials)[c * NPIX + pix];
        cr = fmaf(T, p.x, cr);
        cg = fmaf(T, p.y, cg);
        cb = fmaf(T, p.z, cb);
        T *= p.w;
    }
    out[0 * NPIX + pix] = cr;
    out[1 * NPIX + pix] = cg;
    out[2 * NPIX + pix] = cb;
}

extern "C" void kernel_launch(void* const* d_in, const int* in_sizes, int n_in,
                              void* d_out, int out_size, void* d_ws, size_t ws_size,
                              hipStream_t stream)
{
    const float* coords = (const float*)d_in[0];
    const float* covs   = (const float*)d_in[1];
    const float* colors = (const float*)d_in[2];
    const float* alphas = (const float*)d_in[3];
    const float* Wm     = (const float*)d_in[4];
    const float* Km     = (const float*)d_in[5];

    float* ws = (float*)d_ws;
    float* unsorted = ws;                             // 1024*12 floats = 48 KB
    float* sorted   = ws + N_PTS * PT_STRIDE;         // 48 KB
    float* depths   = ws + 2 * N_PTS * PT_STRIDE;     // 4 KB
    float* partials = ws + 2 * N_PTS * PT_STRIDE + N_PTS;  // 8*16384*4 floats = 2 MB

    k_preprocess<<<dim3((N_PTS + 255) / 256), dim3(256), 0, stream>>>(
        coords, covs, colors, alphas, Wm, Km, unsorted, depths);
    k_sort<<<dim3(N_PTS / 64), dim3(64), 0, stream>>>(unsorted, depths, sorted);
    k_composite<<<dim3(NPIX / 256, NCHUNK), dim3(256), 0, stream>>>(sorted, partials);
    k_combine<<<dim3(NPIX / 256), dim3(256), 0, stream>>>(partials, (float*)d_out);
}

// Round 4
// 110.195 us; speedup vs baseline: 1.8727x; 1.0346x over previous
//
#include <hip/hip_runtime.h>

#define N_PTS   1024
#define IMG_H   128
#define IMG_W   128
#define NPIX    (IMG_H * IMG_W)
#define NEAR    0.01f
#define NSIGMA2 9.0f
#define COV_BLUR 0.3f
#define NCHUNK  32
#define CHUNK_SZ (N_PTS / NCHUNK)     // 32 gaussians per chunk
#define PT_STRIDE 12                  // floats per point record (3 x float4)
#define PXS     4                     // pixels per thread (rows 32 apart)
#define ROWSTEP (NPIX / PXS)          // 4096

// ---------------------------------------------------------------------------
// Kernel 1: fused preprocess + stable depth sort.  16 blocks x 64 threads.
// Each block redundantly computes ALL 1024 depths (3 fma each) into LDS,
// computes the full conic record only for its own 64 points, rank-counts
// from LDS (float4 reads), scatters record to sorted[rank].
// Record: [tz, u, v, ca | 2cb, cc, a, r | g, b, 0, 0]
// ---------------------------------------------------------------------------
__global__ __launch_bounds__(64) void k_sortpre(
    const float* __restrict__ coords,
    const float* __restrict__ covs,
    const float* __restrict__ colors,
    const float* __restrict__ alphas,
    const float* __restrict__ Wm,
    const float* __restrict__ Km,
    float* __restrict__ sorted)
{
    __shared__ __align__(16) float sdep[N_PTS];
    int tid = threadIdx.x;

    float R[3][3], tv[3];
    #pragma unroll
    for (int r = 0; r < 3; r++) {
        #pragma unroll
        for (int c = 0; c < 3; c++) R[r][c] = Wm[r * 4 + c];
        tv[r] = Wm[r * 4 + 3];
    }
    float fx = Km[0], fy = Km[4], cx = Km[2], cy = Km[5];

    // all 1024 depths -> LDS (single source of truth for ordering)
    for (int j = tid; j < N_PTS; j += 64) {
        float c0 = coords[3 * j], c1 = coords[3 * j + 1], c2 = coords[3 * j + 2];
        sdep[j] = R[2][0] * c0 + R[2][1] * c1 + R[2][2] * c2 + tv[2];
    }
    __syncthreads();

    // full preprocess for own point
    int i = blockIdx.x * 64 + tid;
    float c0 = coords[3 * i], c1 = coords[3 * i + 1], c2 = coords[3 * i + 2];
    float tx = R[0][0] * c0 + R[0][1] * c1 + R[0][2] * c2 + tv[0];
    float ty = R[1][0] * c0 + R[1][1] * c1 + R[1][2] * c2 + tv[1];
    float tz = sdep[i];                     // identical bits to ranking key

    float invz = 1.0f / fmaxf(tz, NEAR);
    float u = fx * tx * invz + cx;
    float v = fy * ty * invz + cy;
    float J00 = fx * invz;
    float J02 = -fx * tx * invz * invz;
    float J11 = fy * invz;
    float J12 = -fy * ty * invz * invz;

    float S[3][3];
    #pragma unroll
    for (int r = 0; r < 3; r++)
        #pragma unroll
        for (int c = 0; c < 3; c++) S[r][c] = covs[i * 9 + r * 3 + c];

    float M[3][3];
    #pragma unroll
    for (int r = 0; r < 3; r++)
        #pragma unroll
        for (int c = 0; c < 3; c++)
            M[r][c] = R[r][0] * S[0][c] + R[r][1] * S[1][c] + R[r][2] * S[2][c];
    float Sc[3][3];
    #pragma unroll
    for (int r = 0; r < 3; r++)
        #pragma unroll
        for (int c = 0; c < 3; c++)
            Sc[r][c] = M[r][0] * R[c][0] + M[r][1] * R[c][1] + M[r][2] * R[c][2];

    float js0_0 = J00 * Sc[0][0] + J02 * Sc[2][0];
    float js0_1 = J00 * Sc[0][1] + J02 * Sc[2][1];
    float js0_2 = J00 * Sc[0][2] + J02 * Sc[2][2];
    float js1_1 = J11 * Sc[1][1] + J12 * Sc[2][1];
    float js1_2 = J11 * Sc[1][2] + J12 * Sc[2][2];

    float s00 = J00 * js0_0 + J02 * js0_2 + COV_BLUR;
    float s01 = J11 * js0_1 + J12 * js0_2;
    float s11 = J11 * js1_1 + J12 * js1_2 + COV_BLUR;

    float det = s00 * s11 - s01 * s01;
    float invdet = 1.0f / det;
    float ca  = s11 * invdet;
    float cc  = s00 * invdet;
    float cb2 = -2.0f * s01 * invdet;       // pre-doubled cross term

    float a = fminf(fmaxf(alphas[i], 0.0f), 1.0f);
    if (!(tz > NEAR)) a = 0.0f;             // fold 'valid' mask into alpha

    // stable rank count: key = (depth, original index)
    float my = tz;
    int rank = 0;
    const float4* sd4 = (const float4*)sdep;
    #pragma unroll 8
    for (int jj = 0; jj < N_PTS / 4; jj++) {
        float4 d = sd4[jj];
        int j = 4 * jj;
        rank += (d.x < my) || (d.x == my && (j + 0) < i);
        rank += (d.y < my) || (d.y == my && (j + 1) < i);
        rank += (d.z < my) || (d.z == my && (j + 2) < i);
        rank += (d.w < my) || (d.w == my && (j + 3) < i);
    }

    float4* dst = (float4*)(sorted + rank * PT_STRIDE);
    dst[0] = make_float4(tz, u, v, ca);
    dst[1] = make_float4(cb2, cc, a, colors[3 * i + 0]);
    dst[2] = make_float4(colors[3 * i + 1], colors[3 * i + 2], 0.0f, 0.0f);
}

// ---------------------------------------------------------------------------
// Kernel 2: per-(pixel-quad, chunk) front-to-back compositing of 32 gaussians.
// 4 pixels/thread in the same column, rows 32 apart -> dx / ca*dx^2 / 2cb*dx
// shared across the quad; LDS traffic per pixel-pair cut 4x vs round 2.
// Grid: (4096/256, NCHUNK) = (16, 32) x 256 -> 512 blocks, 8 waves/CU.
// ---------------------------------------------------------------------------
__global__ __launch_bounds__(256) void k_composite(
    const float* __restrict__ sorted, float* __restrict__ partials)
{
    int chunk = blockIdx.y;
    int pix = blockIdx.x * 256 + threadIdx.x;      // 0..4095: rows 0..31

    __shared__ float4 sg[CHUNK_SZ * 3];            // 1.5 KB
    const float4* src = (const float4*)sorted + chunk * CHUNK_SZ * 3;
    if (threadIdx.x < CHUNK_SZ * 3) sg[threadIdx.x] = src[threadIdx.x];
    __syncthreads();

    float px  = (float)(pix & (IMG_W - 1)) + 0.5f;
    float py[PXS];
    #pragma unroll
    for (int s = 0; s < PXS; s++) py[s] = (float)(pix >> 7) + 0.5f + 32.0f * s;

    float T[PXS], cr[PXS], cg[PXS], cb[PXS];
    #pragma unroll
    for (int s = 0; s < PXS; s++) { T[s] = 1.0f; cr[s] = cg[s] = cb[s] = 0.0f; }

    #pragma unroll 4
    for (int k = 0; k < CHUNK_SZ; k++) {
        float4 A = sg[3 * k + 0];   // tz, u, v, ca
        float4 B = sg[3 * k + 1];   // 2cb, cc, a, r
        float4 C = sg[3 * k + 2];   // g, b, -, -
        float dx    = px - A.y;
        float cadxx = A.w * dx * dx;
        float cb2dx = B.x * dx;
        #pragma unroll
        for (int s = 0; s < PXS; s++) {
            float dy  = py[s] - A.z;
            float inr = fmaf(B.y, dy, cb2dx);      // cc*dy + 2cb*dx
            float q   = fmaf(dy, inr, cadxx);      // ca*dx^2 + cc*dy^2 + 2cb*dx*dy
            float e   = __expf(-0.5f * q);
            float apx = fminf(B.z * e, 0.999f);
            apx = (q <= NSIGMA2) ? apx : 0.0f;
            float w = T[s] * apx;
            cr[s] = fmaf(w, B.w, cr[s]);
            cg[s] = fmaf(w, C.x, cg[s]);
            cb[s] = fmaf(w, C.y, cb[s]);
            T[s]  = fmaf(-apx, T[s], T[s]);
        }
    }

    #pragma unroll
    for (int s = 0; s < PXS; s++)
        ((float4*)partials)[chunk * NPIX + pix + s * ROWSTEP] =
            make_float4(cr[s], cg[s], cb[s], T[s]);
}

// ---------------------------------------------------------------------------
// Kernel 3: fold the NCHUNK partials per pixel in depth order, emit fp32 CHW.
// ---------------------------------------------------------------------------
__global__ __launch_bounds__(128) void k_combine(
    const float* __restrict__ partials, float* __restrict__ out)
{
    int pix = blockIdx.x * 128 + threadIdx.x;      // 0..16383, 128 blocks
    float T = 1.0f, r = 0.0f, g = 0.0f, b = 0.0f;
    #pragma unroll
    for (int c = 0; c < NCHUNK; c++) {
        float4 p = ((const float4*)partials)[c * NPIX + pix];
        r = fmaf(T, p.x, r);
        g = fmaf(T, p.y, g);
        b = fmaf(T, p.z, b);
        T *= p.w;
    }
    out[0 * NPIX + pix] = r;
    out[1 * NPIX + pix] = g;
    out[2 * NPIX + pix] = b;
}

extern "C" void kernel_launch(void* const* d_in, const int* in_sizes, int n_in,
                              void* d_out, int out_size, void* d_ws, size_t ws_size,
                              hipStream_t stream)
{
    const float* coords = (const float*)d_in[0];
    const float* covs   = (const float*)d_in[1];
    const float* colors = (const float*)d_in[2];
    const float* alphas = (const float*)d_in[3];
    const float* Wm     = (const float*)d_in[4];
    const float* Km     = (const float*)d_in[5];

    float* ws = (float*)d_ws;
    float* sorted   = ws;                          // 1024*12 floats = 48 KB
    float* partials = ws + N_PTS * PT_STRIDE;      // 32*16384*4 floats = 8 MB

    k_sortpre<<<dim3(N_PTS / 64), dim3(64), 0, stream>>>(
        coords, covs, colors, alphas, Wm, Km, sorted);
    k_composite<<<dim3(ROWSTEP / 256, NCHUNK), dim3(256), 0, stream>>>(sorted, partials);
    k_combine<<<dim3(NPIX / 128), dim3(128), 0, stream>>>(partials, (float*)d_out);
}